// Round 12
// baseline (642.654 us; speedup 1.0000x reference)
//
#include <hip/hip_runtime.h>

typedef _Float16 f16;
typedef unsigned int u32;
typedef f16 f16x8 __attribute__((ext_vector_type(8)));
typedef f16 f16x4 __attribute__((ext_vector_type(4)));
typedef __fp16 h16x2 __attribute__((ext_vector_type(2)));
typedef float f32x4 __attribute__((ext_vector_type(4)));

// N=4,T=8,H=64,W=64,C=512, WS=8, heads=8, head_dim=64
// windows = 2048, tokens/window = 64, M = 131072, K = 512, Nqkv = 1536

__device__ __forceinline__ int src_row(int m) {
    int win = m >> 6, s = m & 63;
    return ((win >> 6) << 12) | (((win >> 3) & 7) << 9) | ((s >> 3) << 6) |
           ((win & 7) << 3) | (s & 7);
}

__device__ __forceinline__ void gload_lds16(const void* g, void* lds) {
    __builtin_amdgcn_global_load_lds(
        (const __attribute__((address_space(1))) u32*)g,
        (__attribute__((address_space(3))) u32*)lds, 16, 0, 0);
}

__device__ __forceinline__ f16x8 pack8(f32x4 lo, f32x4 hi) {
    h16x2 a = __builtin_amdgcn_cvt_pkrtz(lo[0], lo[1]);
    h16x2 b = __builtin_amdgcn_cvt_pkrtz(lo[2], lo[3]);
    h16x2 c = __builtin_amdgcn_cvt_pkrtz(hi[0], hi[1]);
    h16x2 d = __builtin_amdgcn_cvt_pkrtz(hi[2], hi[3]);
    f16x8 r;
    r[0] = (f16)a[0]; r[1] = (f16)a[1]; r[2] = (f16)b[0]; r[3] = (f16)b[1];
    r[4] = (f16)c[0]; r[5] = (f16)c[1]; r[6] = (f16)d[0]; r[7] = (f16)d[1];
    return r;
}

// ---------------- prep: weights fp32 -> fp16 ----------------
__global__ __launch_bounds__(256) void prep_weights_k(
        const float* __restrict__ Wi, const float* __restrict__ Wo,
        f16* __restrict__ Wi_h, f16* __restrict__ Wo_h) {
    int i = blockIdx.x * 256 + threadIdx.x;    // 262144 float4s total
    const float4* src;
    f16* dst;
    int idx;
    if (i < 196608) { src = (const float4*)Wi; dst = Wi_h; idx = i; }
    else            { src = (const float4*)Wo; dst = Wo_h; idx = i - 196608; }
    float4 v = src[idx];
    f16x4 h = {(f16)v.x, (f16)v.y, (f16)v.z, (f16)v.w};
    *(f16x4*)(dst + (size_t)idx * 4) = h;
}

// ---------------- prep: biasT[s][o] = b_in[o] + (o<1024 ? pos[s]·W_in[o] : 0)
__global__ __launch_bounds__(256) void prep_bias_k(
        const float* __restrict__ pos, const float* __restrict__ Wi,
        const float* __restrict__ b_in, float* __restrict__ biasT) {
    int idx = blockIdx.x * 256 + threadIdx.x;   // 64*1536
    int s = idx / 1536, o = idx % 1536;
    float acc = b_in[o];
    if (o < 1024) {
        const float4* p4 = (const float4*)(pos + (size_t)s * 512);
        const float4* w4 = (const float4*)(Wi + (size_t)o * 512);
        #pragma unroll 4
        for (int c = 0; c < 128; ++c) {
            float4 a = p4[c], b = w4[c];
            acc += a.x * b.x + a.y * b.y + a.z * b.z + a.w * b.w;
        }
    }
    biasT[idx] = acc;
}

// ---------------- QKV GEMM: 256x256 tile, BK=32, 8-phase counted-vmcnt.
// A read DIRECTLY from x (fp32, window-permuted per-lane source), staged to LDS
// as fp32, converted to f16 at fragment-read time (cvt_pkrtz). prep_x is gone.
// LDS bytes: A 4 slots x 16 KB @0, B 4 slots x 8 KB @65536 (96 KB main loop;
// V-transpose epilogue reuses the 128 KB allocation).
__global__ void __launch_bounds__(512, 2) qkv_gemm8_k(
        const float* __restrict__ x, const f16* __restrict__ Wh,
        const float* __restrict__ biasT, f16* __restrict__ qk,
        f16* __restrict__ vT, int nblk, int m0) {
    extern __shared__ f16 lds[];
    char* L = (char*)lds;
    int tid = threadIdx.x;
    int lane = tid & 63, wid = tid >> 6;
    int l15 = lane & 15, g = lane >> 4;
    int wm = wid >> 2, wn = wid & 3;            // 2M x 4N waves, wave tile 128x64
    int sid = (blockIdx.x & 7) * (nblk >> 3) + (blockIdx.x >> 3);
    int bm = sid / 6, bn = sid % 6;
    int m0g = m0 + bm * 256;                    // global row base of A panel
    const f16* Bp = Wh + (size_t)bn * 256 * 512;

    // A staging: half h = 128 rows x 32 f32 = 16 KB = 2 gloads/thread.
    // linear LDS position c holds original chunk (c&7)^(r&7) -> pre-swizzled source.
    auto stageA = [&](int tt, int h) {
        int dst = ((tt & 1) * 2 + h) * 16384 + wid * 1024;
        #pragma unroll
        for (int i = 0; i < 2; ++i) {
            int c = i * 512 + tid;
            int r = c >> 3, p = c & 7;
            const float* src = x + (size_t)src_row(m0g + h * 128 + r) * 512
                                 + tt * 32 + ((p ^ (r & 7)) * 4);
            gload_lds16(src, (void*)(L + dst + i * 8192));
        }
    };
    // B staging: half h = 128 rows x 32 f16 = 8 KB = 1 gload/thread.
    auto stageB = [&](int tt, int h) {
        int dst = 65536 + ((tt & 1) * 2 + h) * 8192 + wid * 1024;
        int r = tid >> 2, p = tid & 3;
        int pr = (r & 3) ^ ((r >> 2) & 3);
        const f16* src = Bp + (size_t)(h * 128 + r) * 512 + tt * 32 + ((p ^ pr) * 8);
        gload_lds16(src, (void*)(L + dst));
    };

    f32x4 acc[8][4];
    f32x4 zero4 = {0.f, 0.f, 0.f, 0.f};
    #pragma unroll
    for (int a = 0; a < 8; ++a)
        #pragma unroll
        for (int b = 0; b < 4; ++b) acc[a][b] = zero4;
    f16x8 bf[4];

    stageA(0, 0); stageA(0, 1); stageB(0, 0); stageB(0, 1);
    stageA(1, 0); stageA(1, 1); stageB(1, 0); stageB(1, 1);
    asm volatile("s_waitcnt vmcnt(0)" ::: "memory");
    __builtin_amdgcn_s_barrier();

    for (int tt = 0; tt < 16; ++tt) {
        const char* Ab = L + ((tt & 1) * 2 + wm) * 16384;
        const char* Bb = L + 65536 + ((tt & 1) * 2 + (wn >> 1)) * 8192;
        #pragma unroll
        for (int q = 0; q < 4; ++q) {
            f16x8 af[2];
            #pragma unroll
            for (int ml = 0; ml < 2; ++ml) {
                int rr = (q * 2 + ml) * 16 + l15;
                f32x4 lo = *(const f32x4*)(Ab + rr * 128 + (((2 * g) ^ (rr & 7)) * 16));
                f32x4 hi = *(const f32x4*)(Ab + rr * 128 + (((2 * g + 1) ^ (rr & 7)) * 16));
                af[ml] = pack8(lo, hi);
            }
            if (q == 0) {
                #pragma unroll
                for (int nf = 0; nf < 4; ++nf) {
                    int rb = (wn & 1) * 64 + nf * 16 + l15;
                    int pr = (rb & 3) ^ ((rb >> 2) & 3);
                    bf[nf] = *(const f16x8*)(Bb + rb * 64 + ((g ^ pr) * 16));
                }
            }
            // staging: q0/q1 -> A(tt+1) halves, q2/q3 -> B(tt+2) halves
            if (q <= 1) {
                if (tt >= 1 && tt + 1 <= 15) stageA(tt + 1, q);
            } else {
                if (tt + 2 <= 15) stageB(tt + 2, q - 2);
            }
            __builtin_amdgcn_s_barrier();
            __builtin_amdgcn_s_setprio(1);
            #pragma unroll
            for (int ml = 0; ml < 2; ++ml)
                #pragma unroll
                for (int nf = 0; nf < 4; ++nf)
                    acc[q * 2 + ml][nf] = __builtin_amdgcn_mfma_f32_16x16x32_f16(
                        af[ml], bf[nf], acc[q * 2 + ml][nf], 0, 0, 0);
            __builtin_amdgcn_s_setprio(0);
            if (q == 3) {
                if (tt < 14)       asm volatile("s_waitcnt vmcnt(2)" ::: "memory");
                else if (tt == 14) asm volatile("s_waitcnt vmcnt(0)" ::: "memory");
            }
            __builtin_amdgcn_s_barrier();
        }
    }

    int browg = bm * 256 + wm * 128;
    if (bn < 4) {
        // Q,K: bias (row-dependent) + f16 store, row stride 1024 (proven granularity)
        #pragma unroll
        for (int mf = 0; mf < 8; ++mf) {
            #pragma unroll
            for (int nf = 0; nf < 4; ++nf) {
                int col = bn * 256 + wn * 64 + nf * 16 + l15;
                #pragma unroll
                for (int j = 0; j < 4; ++j) {
                    int row = browg + mf * 16 + g * 4 + j;
                    float v = acc[mf][nf][j] + biasT[(row & 63) * 1536 + col];
                    qk[(size_t)row * 1024 + col] = (f16)v;
                }
            }
        }
    } else {
        // V: bias row-independent. Transpose via LDS -> vT[win][head][d][s]
        __syncthreads();
        char* T = L;   // 256 d-rows x 512 B, XOR-swizzled
        int bn2 = bn - 4;
        #pragma unroll
        for (int mf = 0; mf < 8; ++mf) {
            #pragma unroll
            for (int nf = 0; nf < 4; ++nf) {
                int dl = wn * 64 + nf * 16 + l15;           // 0..255
                float bo = biasT[1024 + bn2 * 256 + dl];
                #pragma unroll
                for (int j = 0; j < 4; ++j) {
                    int sl = wm * 128 + mf * 16 + g * 4 + j;  // 0..255
                    *(f16*)(T + dl * 512 + ((sl * 2) ^ ((dl & 7) << 4))) =
                        (f16)(acc[mf][nf][j] + bo);
                }
            }
        }
        __syncthreads();
        #pragma unroll
        for (int r = 0; r < 16; ++r) {
            int c = r * 512 + tid;              // 0..8191 chunks of 16B
            int dl = c >> 5, s0 = (c & 31) * 8;
            f16x8 v = *(const f16x8*)(T + dl * 512 + ((s0 * 2) ^ ((dl & 7) << 4)));
            int gcol = bn2 * 256 + dl;          // 0..511
            int head = gcol >> 6, dd = gcol & 63;
            int win = bm * 4 + (s0 >> 6);
            *(f16x8*)(vT + (size_t)win * 32768 + head * 4096 + dd * 64 + (s0 & 63)) = v;
        }
    }
}

// ---------------- attention: swapped QK^T in-lane softmax + setprio (R10, best) ----------------
__global__ __launch_bounds__(512) void attn_k(
        const f16* __restrict__ qk, const f16* __restrict__ vT,
        f16* __restrict__ attn_h) {
    __shared__ __align__(16) char S[64 * 1024];   // 8 heads x 8 KB P-slices
    int tid = threadIdx.x;
    int lane = tid & 63, h = tid >> 6;   // wave = head
    int l15 = lane & 15, g = lane >> 4;
    const f16* baseqk = qk + (size_t)blockIdx.x * 65536;
    const f16* basev  = vT + (size_t)blockIdx.x * 32768 + h * 4096;
    int qc = h * 64, kc = 512 + h * 64;

    f32x4 zero4 = {0.f, 0.f, 0.f, 0.f};
    f32x4 acc[4][4];
    #pragma unroll
    for (int a = 0; a < 4; ++a)
        #pragma unroll
        for (int b = 0; b < 4; ++b) acc[a][b] = zero4;

    {   // S^T = K @ Q^T : acc[ki][qi] = S[key=ki*16+g*4+j][query=qi*16+l15]
        f16x8 qf[4][2], kf[4][2];
        #pragma unroll
        for (int mf = 0; mf < 4; ++mf)
            #pragma unroll
            for (int ks = 0; ks < 2; ++ks)
                qf[mf][ks] = *reinterpret_cast<const f16x8*>(baseqk + (size_t)(mf * 16 + l15) * 1024 + qc + ks * 32 + g * 8);
        #pragma unroll
        for (int nf = 0; nf < 4; ++nf)
            #pragma unroll
            for (int ks = 0; ks < 2; ++ks)
                kf[nf][ks] = *reinterpret_cast<const f16x8*>(baseqk + (size_t)(nf * 16 + l15) * 1024 + kc + ks * 32 + g * 8);
        __builtin_amdgcn_s_setprio(1);
        #pragma unroll
        for (int ks = 0; ks < 2; ++ks)
            #pragma unroll
            for (int ki = 0; ki < 4; ++ki)
                #pragma unroll
                for (int qi = 0; qi < 4; ++qi)
                    acc[ki][qi] = __builtin_amdgcn_mfma_f32_16x16x32_f16(kf[ki][ks], qf[qi][ks], acc[ki][qi], 0, 0, 0);
        __builtin_amdgcn_s_setprio(0);
    }

    // V fragments: contiguous f16x8 reads (B-frag: lane holds V[s][d=l15])
    f16x8 vf[4][2];
    #pragma unroll
    for (int nf = 0; nf < 4; ++nf)
        #pragma unroll
        for (int ks = 0; ks < 2; ++ks)
            vf[nf][ks] = *reinterpret_cast<const f16x8*>(basev + (nf * 16 + l15) * 64 + ks * 32 + g * 8);

    // in-lane softmax per query (16 keys in-lane + 2+2 shfl over g); P^T -> LDS [query][key]
    char* Sh = S + h * 8192;
    #pragma unroll
    for (int qi = 0; qi < 4; ++qi) {
        float mx = -1e30f;
        #pragma unroll
        for (int ki = 0; ki < 4; ++ki)
            #pragma unroll
            for (int j = 0; j < 4; ++j) mx = fmaxf(mx, acc[ki][qi][j]);
        mx = fmaxf(mx, __shfl_xor(mx, 16));
        mx = fmaxf(mx, __shfl_xor(mx, 32));
        float sum = 0.f;
        #pragma unroll
        for (int ki = 0; ki < 4; ++ki)
            #pragma unroll
            for (int j = 0; j < 4; ++j) {
                float e = __expf((acc[ki][qi][j] - mx) * 0.125f);
                acc[ki][qi][j] = e;
                sum += e;
            }
        sum += __shfl_xor(sum, 16);
        sum += __shfl_xor(sum, 32);
        float rinv = __fdividef(1.0f, sum);
        int qrow = qi * 16 + l15;
        char* rowp = Sh + qrow * 128;
        int sw = (qrow & 7) << 4;
        #pragma unroll
        for (int ki = 0; ki < 4; ++ki)
            #pragma unroll
            for (int j = 0; j < 4; ++j)
                *(f16*)(rowp + (((ki * 16 + g * 4 + j) * 2) ^ sw)) = (f16)(acc[ki][qi][j] * rinv);
    }

    // out_h = P @ V  (own slice; wave-local, no barrier)
    f32x4 acc2[4][4];
    #pragma unroll
    for (int a = 0; a < 4; ++a)
        #pragma unroll
        for (int b = 0; b < 4; ++b) acc2[a][b] = zero4;
    __builtin_amdgcn_s_setprio(1);
    #pragma unroll
    for (int ks = 0; ks < 2; ++ks)
        #pragma unroll
        for (int mf = 0; mf < 4; ++mf) {
            int rr = mf * 16 + l15;
            f16x8 pa = *reinterpret_cast<const f16x8*>(Sh + rr * 128 + (((ks * 32 + g * 8) * 2) ^ ((rr & 7) << 4)));
            #pragma unroll
            for (int nf = 0; nf < 4; ++nf)
                acc2[mf][nf] = __builtin_amdgcn_mfma_f32_16x16x32_f16(pa, vf[nf][ks], acc2[mf][nf], 0, 0, 0);
        }
    __builtin_amdgcn_s_setprio(0);

    f16* dst = attn_h + (size_t)blockIdx.x * 64 * 512 + h * 64;
    #pragma unroll
    for (int mf = 0; mf < 4; ++mf)
        #pragma unroll
        for (int nf = 0; nf < 4; ++nf)
            #pragma unroll
            for (int j = 0; j < 4; ++j)
                dst[(size_t)(mf * 16 + g * 4 + j) * 512 + nf * 16 + l15] = (f16)acc2[mf][nf][j];
}

// ---------------- output projection: 8-phase 256x256 GEMM + scatter (R10, best) ----------------
__global__ void __launch_bounds__(512, 2) proj_gemm8_k(
        const f16* __restrict__ attn_h, const f16* __restrict__ Woh,
        const float* __restrict__ b_out, float* __restrict__ out, int nblk, int m0) {
    extern __shared__ f16 lds[];
    int tid = threadIdx.x;
    int lane = tid & 63, wid = tid >> 6;
    int l15 = lane & 15, g = lane >> 4;
    int wm = wid >> 2, wn = wid & 3;
    int sid = (blockIdx.x & 7) * (nblk >> 3) + (blockIdx.x >> 3);
    int bm = sid >> 1, bn = sid & 1;
    const f16* Ap = attn_h + (size_t)bm * 256 * 512;
    const f16* Bp = Woh + (size_t)bn * 256 * 512;

    int li0 = tid, li1 = tid + 512;
    int r0 = li0 >> 3, c0 = li0 & 7, r1 = li1 >> 3, c1 = li1 & 7;
    int off0 = r0 * 512 + ((c0 ^ (r0 & 7)) * 8);
    int off1 = r1 * 512 + ((c1 ^ (r1 & 7)) * 8);

    auto stage = [&](const f16* panel, int ldsbase, int tt, int h) {
        int tb = tt & 1;
        int dst = ldsbase + (tb * 2 + h) * 8192 + wid * 512;
        const f16* src = panel + h * 65536 + tt * 64;
        gload_lds16(src + off0, (void*)&lds[dst]);
        gload_lds16(src + off1, (void*)&lds[dst + 4096]);
    };

    f32x4 acc[8][4];
    f32x4 zero4 = {0.f, 0.f, 0.f, 0.f};
    #pragma unroll
    for (int a = 0; a < 8; ++a)
        #pragma unroll
        for (int b = 0; b < 4; ++b) acc[a][b] = zero4;
    f16x8 bf[4][2];

    stage(Ap, 0, 0, 0); stage(Ap, 0, 0, 1);
    stage(Bp, 32768, 0, 0); stage(Bp, 32768, 0, 1);
    stage(Ap, 0, 1, 0); stage(Ap, 0, 1, 1);
    stage(Bp, 32768, 1, 0); stage(Bp, 32768, 1, 1);
    asm volatile("s_waitcnt vmcnt(0)" ::: "memory");
    __builtin_amdgcn_s_barrier();

    #pragma unroll
    for (int tt = 0; tt < 8; ++tt) {
        int tb = tt & 1;
        const f16* Ab = &lds[(tb * 2 + wm) * 8192];
        const f16* Bb = &lds[32768 + (tb * 2 + (wn >> 1)) * 8192];
        #pragma unroll
        for (int q = 0; q < 4; ++q) {
            f16x8 af[2][2];
            #pragma unroll
            for (int ml = 0; ml < 2; ++ml) {
                int rr = (q * 2 + ml) * 16 + l15;
                #pragma unroll
                for (int ks = 0; ks < 2; ++ks)
                    af[ml][ks] = *(const f16x8*)&Ab[rr * 64 + (((ks * 4 + g) ^ (rr & 7)) * 8)];
            }
            if (q == 0) {
                #pragma unroll
                for (int nf = 0; nf < 4; ++nf) {
                    int rb = (wn & 1) * 64 + nf * 16 + l15;
                    #pragma unroll
                    for (int ks = 0; ks < 2; ++ks)
                        bf[nf][ks] = *(const f16x8*)&Bb[rb * 64 + (((ks * 4 + g) ^ (rb & 7)) * 8)];
                }
            }
            if (q <= 1) {
                if ((tt & 1) ? (tt + 1 < 8) : (tt >= 2)) stage(Ap, 0, tt + 1, q);
            } else {
                if (tt + 2 < 8) stage(Bp, 32768, tt + 2, q - 2);
            }
            __builtin_amdgcn_s_barrier();
            __builtin_amdgcn_s_setprio(1);
            #pragma unroll
            for (int ml = 0; ml < 2; ++ml)
                #pragma unroll
                for (int nf = 0; nf < 4; ++nf)
                    #pragma unroll
                    for (int ks = 0; ks < 2; ++ks)
                        acc[q * 2 + ml][nf] = __builtin_amdgcn_mfma_f32_16x16x32_f16(
                            af[ml][ks], bf[nf][ks], acc[q * 2 + ml][nf], 0, 0, 0);
            __builtin_amdgcn_s_setprio(0);
            if (q == 3) {
                if (tt < 6)       asm volatile("s_waitcnt vmcnt(4)" ::: "memory");
                else if (tt == 6) asm volatile("s_waitcnt vmcnt(0)" ::: "memory");
            }
            __builtin_amdgcn_s_barrier();
        }
    }

    int browg = bm * 256 + wm * 128, bcolg = bn * 256 + wn * 64;
    #pragma unroll
    for (int nf = 0; nf < 4; ++nf) {
        int col = bcolg + nf * 16 + l15;
        float bo = b_out[col];
        #pragma unroll
        for (int mf = 0; mf < 8; ++mf) {
            #pragma unroll
            for (int j = 0; j < 4; ++j) {
                int srow = src_row(m0 + browg + mf * 16 + g * 4 + j);
                out[(size_t)srow * 512 + col] = acc[mf][nf][j] + bo;
            }
        }
    }
}

extern "C" void kernel_launch(void* const* d_in, const int* in_sizes, int n_in,
                              void* d_out, int out_size, void* d_ws, size_t ws_size,
                              hipStream_t stream) {
    (void)in_sizes; (void)n_in; (void)out_size;
    const float* x     = (const float*)d_in[0];
    const float* pos   = (const float*)d_in[1];
    const float* W_in  = (const float*)d_in[2];
    const float* b_in  = (const float*)d_in[3];
    const float* W_out = (const float*)d_in[4];
    const float* b_out = (const float*)d_in[5];
    float* out = (float*)d_out;

    char* ws = (char*)d_ws;
    f16*   Wi_h  = (f16*)ws;                  // 1,572,864 B
    f16*   Wo_h  = (f16*)(ws + 1572864);      //   524,288 B
    float* biasT = (float*)(ws + 2097152);    //   393,216 B
    const size_t fixed = 2490368;

    // 4096 B per row: qk (2048) + vT (1024) + attn_h (1024). No xh anymore.
    int chunks = 4;
    while (chunks < 64) {
        size_t need = fixed + ((size_t)131072 / chunks) * 4096;
        if (need <= ws_size) break;
        chunks <<= 1;
    }
    int Mc = 131072 / chunks;
    f16* qk     = (f16*)(ws + fixed);
    f16* vT     = (f16*)(ws + fixed + (size_t)Mc * 2048);
    f16* attn_h = (f16*)(ws + fixed + (size_t)Mc * 3072);
    int nblk  = (Mc / 256) * 6;
    int nblkP = (Mc / 256) * 2;

    static_cast<void>(hipFuncSetAttribute((const void*)qkv_gemm8_k,
        hipFuncAttributeMaxDynamicSharedMemorySize, 131072));
    static_cast<void>(hipFuncSetAttribute((const void*)proj_gemm8_k,
        hipFuncAttributeMaxDynamicSharedMemorySize, 131072));

    prep_weights_k<<<1024, 256, 0, stream>>>(W_in, W_out, Wi_h, Wo_h);
    prep_bias_k<<<384, 256, 0, stream>>>(pos, W_in, b_in, biasT);
    for (int c = 0; c < chunks; ++c) {
        int m0 = c * Mc;
        qkv_gemm8_k<<<nblk, 512, 131072, stream>>>(x, Wi_h, biasT, qk, vT, nblk, m0);
        attn_k<<<Mc / 64, 512, 0, stream>>>(qk, vT, attn_h);
        proj_gemm8_k<<<nblkP, 512, 131072, stream>>>(attn_h, Wo_h, b_out, out, nblkP, m0);
    }
}

// Round 13
// 582.913 us; speedup vs baseline: 1.1025x; 1.1025x over previous
//
#include <hip/hip_runtime.h>

typedef _Float16 f16;
typedef unsigned int u32;
typedef f16 f16x8 __attribute__((ext_vector_type(8)));
typedef f16 f16x4 __attribute__((ext_vector_type(4)));
typedef float f32x4 __attribute__((ext_vector_type(4)));

// N=4,T=8,H=64,W=64,C=512, WS=8, heads=8, head_dim=64
// windows = 2048, tokens/window = 64, M = 131072, K = 512, Nqkv = 1536

__device__ __forceinline__ int src_row(int m) {
    int win = m >> 6, s = m & 63;
    return ((win >> 6) << 12) | (((win >> 3) & 7) << 9) | ((s >> 3) << 6) |
           ((win & 7) << 3) | (s & 7);
}

__device__ __forceinline__ void gload_lds16(const void* g, void* lds) {
    __builtin_amdgcn_global_load_lds(
        (const __attribute__((address_space(1))) u32*)g,
        (__attribute__((address_space(3))) u32*)lds, 16, 0, 0);
}

// ---------------- prep: weights fp32 -> fp16 ----------------
__global__ __launch_bounds__(256) void prep_weights_k(
        const float* __restrict__ Wi, const float* __restrict__ Wo,
        f16* __restrict__ Wi_h, f16* __restrict__ Wo_h) {
    int i = blockIdx.x * 256 + threadIdx.x;    // 262144 float4s total
    const float4* src;
    f16* dst;
    int idx;
    if (i < 196608) { src = (const float4*)Wi; dst = Wi_h; idx = i; }
    else            { src = (const float4*)Wo; dst = Wo_h; idx = i - 196608; }
    float4 v = src[idx];
    f16x4 h = {(f16)v.x, (f16)v.y, (f16)v.z, (f16)v.w};
    *(f16x4*)(dst + (size_t)idx * 4) = h;
}

// ---------------- prep: biasT[s][o] = b_in[o] + (o<1024 ? pos[s]·W_in[o] : 0)
__global__ __launch_bounds__(256) void prep_bias_k(
        const float* __restrict__ pos, const float* __restrict__ Wi,
        const float* __restrict__ b_in, float* __restrict__ biasT) {
    int idx = blockIdx.x * 256 + threadIdx.x;   // 64*1536
    int s = idx / 1536, o = idx % 1536;
    float acc = b_in[o];
    if (o < 1024) {
        const float4* p4 = (const float4*)(pos + (size_t)s * 512);
        const float4* w4 = (const float4*)(Wi + (size_t)o * 512);
        #pragma unroll 4
        for (int c = 0; c < 128; ++c) {
            float4 a = p4[c], b = w4[c];
            acc += a.x * b.x + a.y * b.y + a.z * b.z + a.w * b.w;
        }
    }
    biasT[idx] = acc;
}

// ---------------- prep: x fp32 -> window-major f16 ----------------
__global__ __launch_bounds__(256) void prep_x_k(
        const float* __restrict__ x, f16* __restrict__ xh, int m0) {
    int i = blockIdx.x * 256 + threadIdx.x;    // Mc*64
    int ml = i >> 6, c8 = (i & 63) * 8;
    int sr = src_row(m0 + ml);
    const float4* s4 = (const float4*)(x + (size_t)sr * 512 + c8);
    float4 a = s4[0], b = s4[1];
    f16x8 hv = {(f16)a.x, (f16)a.y, (f16)a.z, (f16)a.w,
                (f16)b.x, (f16)b.y, (f16)b.z, (f16)b.w};
    *(f16x8*)(xh + (size_t)ml * 512 + c8) = hv;
}

// ---------------- QKV GEMM: 256x256 tile, BK=64, 8-phase counted-vmcnt (R5-proven)
// Q,K cols (bn<4) -> qk[row][0..1023]; V cols (bn>=4) -> vT[win][head][d][s] via LDS transpose
__global__ void __launch_bounds__(512, 2) qkv_gemm8_k(
        const f16* __restrict__ xh, const f16* __restrict__ Wh,
        const float* __restrict__ biasT, f16* __restrict__ qk,
        f16* __restrict__ vT, int nblk) {
    extern __shared__ f16 lds[];
    int tid = threadIdx.x;
    int lane = tid & 63, wid = tid >> 6;
    int l15 = lane & 15, g = lane >> 4;
    int wm = wid >> 2, wn = wid & 3;            // 2M x 4N waves, wave tile 128x64
    int sid = (blockIdx.x & 7) * (nblk >> 3) + (blockIdx.x >> 3);
    int bm = sid / 6, bn = sid % 6;
    const f16* Ap = xh + (size_t)bm * 256 * 512;
    const f16* Bp = Wh + (size_t)bn * 256 * 512;

    int li0 = tid, li1 = tid + 512;
    int r0 = li0 >> 3, c0 = li0 & 7, r1 = li1 >> 3, c1 = li1 & 7;
    int off0 = r0 * 512 + ((c0 ^ (r0 & 7)) * 8);
    int off1 = r1 * 512 + ((c1 ^ (r1 & 7)) * 8);

    auto stage = [&](const f16* panel, int ldsbase, int tt, int h) {
        int tb = tt & 1;
        int dst = ldsbase + (tb * 2 + h) * 8192 + wid * 512;   // wave-uniform
        const f16* src = panel + h * 65536 + tt * 64;
        gload_lds16(src + off0, (void*)&lds[dst]);
        gload_lds16(src + off1, (void*)&lds[dst + 4096]);
    };

    f32x4 acc[8][4];
    f32x4 zero4 = {0.f, 0.f, 0.f, 0.f};
    #pragma unroll
    for (int a = 0; a < 8; ++a)
        #pragma unroll
        for (int b = 0; b < 4; ++b) acc[a][b] = zero4;
    f16x8 bf[4][2];

    stage(Ap, 0, 0, 0); stage(Ap, 0, 0, 1);
    stage(Bp, 32768, 0, 0); stage(Bp, 32768, 0, 1);
    stage(Ap, 0, 1, 0); stage(Ap, 0, 1, 1);
    stage(Bp, 32768, 1, 0); stage(Bp, 32768, 1, 1);
    asm volatile("s_waitcnt vmcnt(0)" ::: "memory");
    __builtin_amdgcn_s_barrier();

    #pragma unroll
    for (int tt = 0; tt < 8; ++tt) {
        int tb = tt & 1;
        const f16* Ab = &lds[(tb * 2 + wm) * 8192];
        const f16* Bb = &lds[32768 + (tb * 2 + (wn >> 1)) * 8192];
        #pragma unroll
        for (int q = 0; q < 4; ++q) {
            f16x8 af[2][2];
            #pragma unroll
            for (int ml = 0; ml < 2; ++ml) {
                int rr = (q * 2 + ml) * 16 + l15;
                #pragma unroll
                for (int ks = 0; ks < 2; ++ks)
                    af[ml][ks] = *(const f16x8*)&Ab[rr * 64 + (((ks * 4 + g) ^ (rr & 7)) * 8)];
            }
            if (q == 0) {
                #pragma unroll
                for (int nf = 0; nf < 4; ++nf) {
                    int rb = (wn & 1) * 64 + nf * 16 + l15;
                    #pragma unroll
                    for (int ks = 0; ks < 2; ++ks)
                        bf[nf][ks] = *(const f16x8*)&Bb[rb * 64 + (((ks * 4 + g) ^ (rb & 7)) * 8)];
                }
            }
            if (q <= 1) {
                if ((tt & 1) ? (tt + 1 < 8) : (tt >= 2)) stage(Ap, 0, tt + 1, q);
            } else {
                if (tt + 2 < 8) stage(Bp, 32768, tt + 2, q - 2);
            }
            __builtin_amdgcn_s_barrier();
            __builtin_amdgcn_s_setprio(1);
            #pragma unroll
            for (int ml = 0; ml < 2; ++ml)
                #pragma unroll
                for (int nf = 0; nf < 4; ++nf)
                    #pragma unroll
                    for (int ks = 0; ks < 2; ++ks)
                        acc[q * 2 + ml][nf] = __builtin_amdgcn_mfma_f32_16x16x32_f16(
                            af[ml][ks], bf[nf][ks], acc[q * 2 + ml][nf], 0, 0, 0);
            __builtin_amdgcn_s_setprio(0);
            if (q == 3) {
                if (tt < 6)       asm volatile("s_waitcnt vmcnt(4)" ::: "memory");
                else if (tt == 6) asm volatile("s_waitcnt vmcnt(0)" ::: "memory");
            }
            __builtin_amdgcn_s_barrier();
        }
    }

    int browg = bm * 256 + wm * 128;
    if (bn < 4) {
        // Q,K: bias (row-dependent) + f16 store, row stride 1024 (proven granularity)
        #pragma unroll
        for (int mf = 0; mf < 8; ++mf) {
            #pragma unroll
            for (int nf = 0; nf < 4; ++nf) {
                int col = bn * 256 + wn * 64 + nf * 16 + l15;
                #pragma unroll
                for (int j = 0; j < 4; ++j) {
                    int row = browg + mf * 16 + g * 4 + j;
                    float v = acc[mf][nf][j] + biasT[(row & 63) * 1536 + col];
                    qk[(size_t)row * 1024 + col] = (f16)v;
                }
            }
        }
    } else {
        // V: bias is row-independent. Transpose via LDS -> vT[win][head][d][s]
        __syncthreads();
        char* T = (char*)lds;   // 256 d-rows x 512 B, XOR-swizzled
        int bn2 = bn - 4;
        #pragma unroll
        for (int mf = 0; mf < 8; ++mf) {
            #pragma unroll
            for (int nf = 0; nf < 4; ++nf) {
                int dl = wn * 64 + nf * 16 + l15;           // 0..255
                float bo = biasT[1024 + bn2 * 256 + dl];
                #pragma unroll
                for (int j = 0; j < 4; ++j) {
                    int sl = wm * 128 + mf * 16 + g * 4 + j;  // 0..255
                    *(f16*)(T + dl * 512 + ((sl * 2) ^ ((dl & 7) << 4))) =
                        (f16)(acc[mf][nf][j] + bo);
                }
            }
        }
        __syncthreads();
        #pragma unroll
        for (int r = 0; r < 16; ++r) {
            int c = r * 512 + tid;              // 0..8191 chunks of 16B
            int dl = c >> 5, s0 = (c & 31) * 8;
            f16x8 v = *(const f16x8*)(T + dl * 512 + ((s0 * 2) ^ ((dl & 7) << 4)));
            int gcol = bn2 * 256 + dl;          // 0..511
            int head = gcol >> 6, dd = gcol & 63;
            int win = bm * 4 + (s0 >> 6);
            *(f16x8*)(vT + (size_t)win * 32768 + head * 4096 + dd * 64 + (s0 & 63)) = v;
        }
    }
}

// ---------------- attention: swapped QK^T in-lane softmax + setprio (R10 best) ----------------
__global__ __launch_bounds__(512) void attn_k(
        const f16* __restrict__ qk, const f16* __restrict__ vT,
        f16* __restrict__ attn_h) {
    __shared__ __align__(16) char S[64 * 1024];   // 8 heads x 8 KB P-slices
    int tid = threadIdx.x;
    int lane = tid & 63, h = tid >> 6;   // wave = head
    int l15 = lane & 15, g = lane >> 4;
    const f16* baseqk = qk + (size_t)blockIdx.x * 65536;
    const f16* basev  = vT + (size_t)blockIdx.x * 32768 + h * 4096;
    int qc = h * 64, kc = 512 + h * 64;

    f32x4 zero4 = {0.f, 0.f, 0.f, 0.f};
    f32x4 acc[4][4];
    #pragma unroll
    for (int a = 0; a < 4; ++a)
        #pragma unroll
        for (int b = 0; b < 4; ++b) acc[a][b] = zero4;

    {   // S^T = K @ Q^T : acc[ki][qi] = S[key=ki*16+g*4+j][query=qi*16+l15]
        f16x8 qf[4][2], kf[4][2];
        #pragma unroll
        for (int mf = 0; mf < 4; ++mf)
            #pragma unroll
            for (int ks = 0; ks < 2; ++ks)
                qf[mf][ks] = *reinterpret_cast<const f16x8*>(baseqk + (size_t)(mf * 16 + l15) * 1024 + qc + ks * 32 + g * 8);
        #pragma unroll
        for (int nf = 0; nf < 4; ++nf)
            #pragma unroll
            for (int ks = 0; ks < 2; ++ks)
                kf[nf][ks] = *reinterpret_cast<const f16x8*>(baseqk + (size_t)(nf * 16 + l15) * 1024 + kc + ks * 32 + g * 8);
        __builtin_amdgcn_s_setprio(1);
        #pragma unroll
        for (int ks = 0; ks < 2; ++ks)
            #pragma unroll
            for (int ki = 0; ki < 4; ++ki)
                #pragma unroll
                for (int qi = 0; qi < 4; ++qi)
                    acc[ki][qi] = __builtin_amdgcn_mfma_f32_16x16x32_f16(kf[ki][ks], qf[qi][ks], acc[ki][qi], 0, 0, 0);
        __builtin_amdgcn_s_setprio(0);
    }

    // V fragments: contiguous f16x8 reads (B-frag: lane holds V[s][d=l15])
    f16x8 vf[4][2];
    #pragma unroll
    for (int nf = 0; nf < 4; ++nf)
        #pragma unroll
        for (int ks = 0; ks < 2; ++ks)
            vf[nf][ks] = *reinterpret_cast<const f16x8*>(basev + (nf * 16 + l15) * 64 + ks * 32 + g * 8);

    // in-lane softmax per query (16 keys in-lane + 2+2 shfl over g); P^T -> LDS [query][key]
    char* Sh = S + h * 8192;
    #pragma unroll
    for (int qi = 0; qi < 4; ++qi) {
        float mx = -1e30f;
        #pragma unroll
        for (int ki = 0; ki < 4; ++ki)
            #pragma unroll
            for (int j = 0; j < 4; ++j) mx = fmaxf(mx, acc[ki][qi][j]);
        mx = fmaxf(mx, __shfl_xor(mx, 16));
        mx = fmaxf(mx, __shfl_xor(mx, 32));
        float sum = 0.f;
        #pragma unroll
        for (int ki = 0; ki < 4; ++ki)
            #pragma unroll
            for (int j = 0; j < 4; ++j) {
                float e = __expf((acc[ki][qi][j] - mx) * 0.125f);
                acc[ki][qi][j] = e;
                sum += e;
            }
        sum += __shfl_xor(sum, 16);
        sum += __shfl_xor(sum, 32);
        float rinv = __fdividef(1.0f, sum);
        int qrow = qi * 16 + l15;
        char* rowp = Sh + qrow * 128;
        int sw = (qrow & 7) << 4;
        #pragma unroll
        for (int ki = 0; ki < 4; ++ki)
            #pragma unroll
            for (int j = 0; j < 4; ++j)
                *(f16*)(rowp + (((ki * 16 + g * 4 + j) * 2) ^ sw)) = (f16)(acc[ki][qi][j] * rinv);
    }

    // out_h = P @ V  (own slice; wave-local, no barrier)
    f32x4 acc2[4][4];
    #pragma unroll
    for (int a = 0; a < 4; ++a)
        #pragma unroll
        for (int b = 0; b < 4; ++b) acc2[a][b] = zero4;
    __builtin_amdgcn_s_setprio(1);
    #pragma unroll
    for (int ks = 0; ks < 2; ++ks)
        #pragma unroll
        for (int mf = 0; mf < 4; ++mf) {
            int rr = mf * 16 + l15;
            f16x8 pa = *reinterpret_cast<const f16x8*>(Sh + rr * 128 + (((ks * 32 + g * 8) * 2) ^ ((rr & 7) << 4)));
            #pragma unroll
            for (int nf = 0; nf < 4; ++nf)
                acc2[mf][nf] = __builtin_amdgcn_mfma_f32_16x16x32_f16(pa, vf[nf][ks], acc2[mf][nf], 0, 0, 0);
        }
    __builtin_amdgcn_s_setprio(0);

    f16* dst = attn_h + (size_t)blockIdx.x * 64 * 512 + h * 64;
    #pragma unroll
    for (int mf = 0; mf < 4; ++mf)
        #pragma unroll
        for (int nf = 0; nf < 4; ++nf)
            #pragma unroll
            for (int j = 0; j < 4; ++j)
                dst[(size_t)(mf * 16 + g * 4 + j) * 512 + nf * 16 + l15] = (f16)acc2[mf][nf][j];
}

// ---------------- output projection: 8-phase 256x256 GEMM + scatter (R10 best) ----------------
__global__ void __launch_bounds__(512, 2) proj_gemm8_k(
        const f16* __restrict__ attn_h, const f16* __restrict__ Woh,
        const float* __restrict__ b_out, float* __restrict__ out, int nblk, int m0) {
    extern __shared__ f16 lds[];
    int tid = threadIdx.x;
    int lane = tid & 63, wid = tid >> 6;
    int l15 = lane & 15, g = lane >> 4;
    int wm = wid >> 2, wn = wid & 3;
    int sid = (blockIdx.x & 7) * (nblk >> 3) + (blockIdx.x >> 3);
    int bm = sid >> 1, bn = sid & 1;
    const f16* Ap = attn_h + (size_t)bm * 256 * 512;
    const f16* Bp = Woh + (size_t)bn * 256 * 512;

    int li0 = tid, li1 = tid + 512;
    int r0 = li0 >> 3, c0 = li0 & 7, r1 = li1 >> 3, c1 = li1 & 7;
    int off0 = r0 * 512 + ((c0 ^ (r0 & 7)) * 8);
    int off1 = r1 * 512 + ((c1 ^ (r1 & 7)) * 8);

    auto stage = [&](const f16* panel, int ldsbase, int tt, int h) {
        int tb = tt & 1;
        int dst = ldsbase + (tb * 2 + h) * 8192 + wid * 512;
        const f16* src = panel + h * 65536 + tt * 64;
        gload_lds16(src + off0, (void*)&lds[dst]);
        gload_lds16(src + off1, (void*)&lds[dst + 4096]);
    };

    f32x4 acc[8][4];
    f32x4 zero4 = {0.f, 0.f, 0.f, 0.f};
    #pragma unroll
    for (int a = 0; a < 8; ++a)
        #pragma unroll
        for (int b = 0; b < 4; ++b) acc[a][b] = zero4;
    f16x8 bf[4][2];

    stage(Ap, 0, 0, 0); stage(Ap, 0, 0, 1);
    stage(Bp, 32768, 0, 0); stage(Bp, 32768, 0, 1);
    stage(Ap, 0, 1, 0); stage(Ap, 0, 1, 1);
    stage(Bp, 32768, 1, 0); stage(Bp, 32768, 1, 1);
    asm volatile("s_waitcnt vmcnt(0)" ::: "memory");
    __builtin_amdgcn_s_barrier();

    #pragma unroll
    for (int tt = 0; tt < 8; ++tt) {
        int tb = tt & 1;
        const f16* Ab = &lds[(tb * 2 + wm) * 8192];
        const f16* Bb = &lds[32768 + (tb * 2 + (wn >> 1)) * 8192];
        #pragma unroll
        for (int q = 0; q < 4; ++q) {
            f16x8 af[2][2];
            #pragma unroll
            for (int ml = 0; ml < 2; ++ml) {
                int rr = (q * 2 + ml) * 16 + l15;
                #pragma unroll
                for (int ks = 0; ks < 2; ++ks)
                    af[ml][ks] = *(const f16x8*)&Ab[rr * 64 + (((ks * 4 + g) ^ (rr & 7)) * 8)];
            }
            if (q == 0) {
                #pragma unroll
                for (int nf = 0; nf < 4; ++nf) {
                    int rb = (wn & 1) * 64 + nf * 16 + l15;
                    #pragma unroll
                    for (int ks = 0; ks < 2; ++ks)
                        bf[nf][ks] = *(const f16x8*)&Bb[rb * 64 + (((ks * 4 + g) ^ (rb & 7)) * 8)];
                }
            }
            if (q <= 1) {
                if ((tt & 1) ? (tt + 1 < 8) : (tt >= 2)) stage(Ap, 0, tt + 1, q);
            } else {
                if (tt + 2 < 8) stage(Bp, 32768, tt + 2, q - 2);
            }
            __builtin_amdgcn_s_barrier();
            __builtin_amdgcn_s_setprio(1);
            #pragma unroll
            for (int ml = 0; ml < 2; ++ml)
                #pragma unroll
                for (int nf = 0; nf < 4; ++nf)
                    #pragma unroll
                    for (int ks = 0; ks < 2; ++ks)
                        acc[q * 2 + ml][nf] = __builtin_amdgcn_mfma_f32_16x16x32_f16(
                            af[ml][ks], bf[nf][ks], acc[q * 2 + ml][nf], 0, 0, 0);
            __builtin_amdgcn_s_setprio(0);
            if (q == 3) {
                if (tt < 6)       asm volatile("s_waitcnt vmcnt(4)" ::: "memory");
                else if (tt == 6) asm volatile("s_waitcnt vmcnt(0)" ::: "memory");
            }
            __builtin_amdgcn_s_barrier();
        }
    }

    int browg = bm * 256 + wm * 128, bcolg = bn * 256 + wn * 64;
    #pragma unroll
    for (int nf = 0; nf < 4; ++nf) {
        int col = bcolg + nf * 16 + l15;
        float bo = b_out[col];
        #pragma unroll
        for (int mf = 0; mf < 8; ++mf) {
            #pragma unroll
            for (int j = 0; j < 4; ++j) {
                int srow = src_row(m0 + browg + mf * 16 + g * 4 + j);
                out[(size_t)srow * 512 + col] = acc[mf][nf][j] + bo;
            }
        }
    }
}

extern "C" void kernel_launch(void* const* d_in, const int* in_sizes, int n_in,
                              void* d_out, int out_size, void* d_ws, size_t ws_size,
                              hipStream_t stream) {
    (void)in_sizes; (void)n_in; (void)out_size;
    const float* x     = (const float*)d_in[0];
    const float* pos   = (const float*)d_in[1];
    const float* W_in  = (const float*)d_in[2];
    const float* b_in  = (const float*)d_in[3];
    const float* W_out = (const float*)d_in[4];
    const float* b_out = (const float*)d_in[5];
    float* out = (float*)d_out;

    char* ws = (char*)d_ws;
    f16*   Wi_h  = (f16*)ws;                  // 1,572,864 B
    f16*   Wo_h  = (f16*)(ws + 1572864);      //   524,288 B
    float* biasT = (float*)(ws + 2097152);    //   393,216 B
    const size_t fixed = 2490368;

    // 4096 B per row: xh/attn_h (1024, aliased) + qk (2048) + vT (1024).
    // chunks=4 keeps the ~130 MB working set L3-resident (R5/R10-proven).
    int chunks = 4;
    while (chunks < 64) {
        size_t need = fixed + ((size_t)131072 / chunks) * 4096;
        if (need <= ws_size) break;
        chunks <<= 1;
    }
    int Mc = 131072 / chunks;
    f16* xh = (f16*)(ws + fixed);             // also attn_h (xh dead after qkv_gemm)
    f16* qk = (f16*)(ws + fixed + (size_t)Mc * 1024);
    f16* vT = (f16*)(ws + fixed + (size_t)Mc * 3072);
    int nblk  = (Mc / 256) * 6;
    int nblkP = (Mc / 256) * 2;

    static_cast<void>(hipFuncSetAttribute((const void*)qkv_gemm8_k,
        hipFuncAttributeMaxDynamicSharedMemorySize, 131072));
    static_cast<void>(hipFuncSetAttribute((const void*)proj_gemm8_k,
        hipFuncAttributeMaxDynamicSharedMemorySize, 131072));

    prep_weights_k<<<1024, 256, 0, stream>>>(W_in, W_out, Wi_h, Wo_h);
    prep_bias_k<<<384, 256, 0, stream>>>(pos, W_in, b_in, biasT);
    for (int c = 0; c < chunks; ++c) {
        int m0 = c * Mc;
        prep_x_k<<<Mc / 4, 256, 0, stream>>>(x, xh, m0);
        qkv_gemm8_k<<<nblk, 512, 131072, stream>>>(xh, Wi_h, biasT, qk, vT, nblk);
        attn_k<<<Mc / 64, 512, 0, stream>>>(qk, vT, xh);
        proj_gemm8_k<<<nblkP, 512, 131072, stream>>>(xh, Wo_h, b_out, out, nblkP, m0);
    }
}

// Round 14
// 575.478 us; speedup vs baseline: 1.1167x; 1.0129x over previous
//
#include <hip/hip_runtime.h>

typedef _Float16 f16;
typedef unsigned int u32;
typedef f16 f16x8 __attribute__((ext_vector_type(8)));
typedef f16 f16x4 __attribute__((ext_vector_type(4)));
typedef float f32x4 __attribute__((ext_vector_type(4)));

// N=4,T=8,H=64,W=64,C=512, WS=8, heads=8, head_dim=64
// windows = 2048, tokens/window = 64, M = 131072, K = 512, Nqkv = 1536

__device__ __forceinline__ int src_row(int m) {
    int win = m >> 6, s = m & 63;
    return ((win >> 6) << 12) | (((win >> 3) & 7) << 9) | ((s >> 3) << 6) |
           ((win & 7) << 3) | (s & 7);
}

__device__ __forceinline__ void gload_lds16(const void* g, void* lds) {
    __builtin_amdgcn_global_load_lds(
        (const __attribute__((address_space(1))) u32*)g,
        (__attribute__((address_space(3))) u32*)lds, 16, 0, 0);
}

// ---------------- prep: weights fp32 -> fp16 ----------------
__global__ __launch_bounds__(256) void prep_weights_k(
        const float* __restrict__ Wi, const float* __restrict__ Wo,
        f16* __restrict__ Wi_h, f16* __restrict__ Wo_h) {
    int i = blockIdx.x * 256 + threadIdx.x;    // 262144 float4s total
    const float4* src;
    f16* dst;
    int idx;
    if (i < 196608) { src = (const float4*)Wi; dst = Wi_h; idx = i; }
    else            { src = (const float4*)Wo; dst = Wo_h; idx = i - 196608; }
    float4 v = src[idx];
    f16x4 h = {(f16)v.x, (f16)v.y, (f16)v.z, (f16)v.w};
    *(f16x4*)(dst + (size_t)idx * 4) = h;
}

// ---------------- prep: biasT[s][o] = b_in[o] + (o<1024 ? pos[s]·W_in[o] : 0)
__global__ __launch_bounds__(256) void prep_bias_k(
        const float* __restrict__ pos, const float* __restrict__ Wi,
        const float* __restrict__ b_in, float* __restrict__ biasT) {
    int idx = blockIdx.x * 256 + threadIdx.x;   // 64*1536
    int s = idx / 1536, o = idx % 1536;
    float acc = b_in[o];
    if (o < 1024) {
        const float4* p4 = (const float4*)(pos + (size_t)s * 512);
        const float4* w4 = (const float4*)(Wi + (size_t)o * 512);
        #pragma unroll 4
        for (int c = 0; c < 128; ++c) {
            float4 a = p4[c], b = w4[c];
            acc += a.x * b.x + a.y * b.y + a.z * b.z + a.w * b.w;
        }
    }
    biasT[idx] = acc;
}

// ---------------- prep: x fp32 -> window-major f16 ----------------
__global__ __launch_bounds__(256) void prep_x_k(
        const float* __restrict__ x, f16* __restrict__ xh, int m0) {
    int i = blockIdx.x * 256 + threadIdx.x;    // Mc*64
    int ml = i >> 6, c8 = (i & 63) * 8;
    int sr = src_row(m0 + ml);
    const float4* s4 = (const float4*)(x + (size_t)sr * 512 + c8);
    float4 a = s4[0], b = s4[1];
    f16x8 hv = {(f16)a.x, (f16)a.y, (f16)a.z, (f16)a.w,
                (f16)b.x, (f16)b.y, (f16)b.z, (f16)b.w};
    *(f16x8*)(xh + (size_t)ml * 512 + c8) = hv;
}

// ---------------- QKV GEMM: 256x256 tile, BK=64, 8-phase counted-vmcnt (R5-proven)
// Q,K cols (bn<4) -> qk[row][0..1023]; V cols (bn>=4) -> vT[win][head][d][s] via LDS transpose
__global__ void __launch_bounds__(512, 2) qkv_gemm8_k(
        const f16* __restrict__ xh, const f16* __restrict__ Wh,
        const float* __restrict__ biasT, f16* __restrict__ qk,
        f16* __restrict__ vT, int nblk) {
    extern __shared__ f16 lds[];
    int tid = threadIdx.x;
    int lane = tid & 63, wid = tid >> 6;
    int l15 = lane & 15, g = lane >> 4;
    int wm = wid >> 2, wn = wid & 3;            // 2M x 4N waves, wave tile 128x64
    int sid = (blockIdx.x & 7) * (nblk >> 3) + (blockIdx.x >> 3);
    int bm = sid / 6, bn = sid % 6;
    const f16* Ap = xh + (size_t)bm * 256 * 512;
    const f16* Bp = Wh + (size_t)bn * 256 * 512;

    int li0 = tid, li1 = tid + 512;
    int r0 = li0 >> 3, c0 = li0 & 7, r1 = li1 >> 3, c1 = li1 & 7;
    int off0 = r0 * 512 + ((c0 ^ (r0 & 7)) * 8);
    int off1 = r1 * 512 + ((c1 ^ (r1 & 7)) * 8);

    auto stage = [&](const f16* panel, int ldsbase, int tt, int h) {
        int tb = tt & 1;
        int dst = ldsbase + (tb * 2 + h) * 8192 + wid * 512;   // wave-uniform
        const f16* src = panel + h * 65536 + tt * 64;
        gload_lds16(src + off0, (void*)&lds[dst]);
        gload_lds16(src + off1, (void*)&lds[dst + 4096]);
    };

    f32x4 acc[8][4];
    f32x4 zero4 = {0.f, 0.f, 0.f, 0.f};
    #pragma unroll
    for (int a = 0; a < 8; ++a)
        #pragma unroll
        for (int b = 0; b < 4; ++b) acc[a][b] = zero4;
    f16x8 bf[4][2];

    stage(Ap, 0, 0, 0); stage(Ap, 0, 0, 1);
    stage(Bp, 32768, 0, 0); stage(Bp, 32768, 0, 1);
    stage(Ap, 0, 1, 0); stage(Ap, 0, 1, 1);
    stage(Bp, 32768, 1, 0); stage(Bp, 32768, 1, 1);
    asm volatile("s_waitcnt vmcnt(0)" ::: "memory");
    __builtin_amdgcn_s_barrier();

    #pragma unroll
    for (int tt = 0; tt < 8; ++tt) {
        int tb = tt & 1;
        const f16* Ab = &lds[(tb * 2 + wm) * 8192];
        const f16* Bb = &lds[32768 + (tb * 2 + (wn >> 1)) * 8192];
        #pragma unroll
        for (int q = 0; q < 4; ++q) {
            f16x8 af[2][2];
            #pragma unroll
            for (int ml = 0; ml < 2; ++ml) {
                int rr = (q * 2 + ml) * 16 + l15;
                #pragma unroll
                for (int ks = 0; ks < 2; ++ks)
                    af[ml][ks] = *(const f16x8*)&Ab[rr * 64 + (((ks * 4 + g) ^ (rr & 7)) * 8)];
            }
            if (q == 0) {
                #pragma unroll
                for (int nf = 0; nf < 4; ++nf) {
                    int rb = (wn & 1) * 64 + nf * 16 + l15;
                    #pragma unroll
                    for (int ks = 0; ks < 2; ++ks)
                        bf[nf][ks] = *(const f16x8*)&Bb[rb * 64 + (((ks * 4 + g) ^ (rb & 7)) * 8)];
                }
            }
            if (q <= 1) {
                if ((tt & 1) ? (tt + 1 < 8) : (tt >= 2)) stage(Ap, 0, tt + 1, q);
            } else {
                if (tt + 2 < 8) stage(Bp, 32768, tt + 2, q - 2);
            }
            __builtin_amdgcn_s_barrier();
            __builtin_amdgcn_s_setprio(1);
            #pragma unroll
            for (int ml = 0; ml < 2; ++ml)
                #pragma unroll
                for (int nf = 0; nf < 4; ++nf)
                    #pragma unroll
                    for (int ks = 0; ks < 2; ++ks)
                        acc[q * 2 + ml][nf] = __builtin_amdgcn_mfma_f32_16x16x32_f16(
                            af[ml][ks], bf[nf][ks], acc[q * 2 + ml][nf], 0, 0, 0);
            __builtin_amdgcn_s_setprio(0);
            if (q == 3) {
                if (tt < 6)       asm volatile("s_waitcnt vmcnt(4)" ::: "memory");
                else if (tt == 6) asm volatile("s_waitcnt vmcnt(0)" ::: "memory");
            }
            __builtin_amdgcn_s_barrier();
        }
    }

    int browg = bm * 256 + wm * 128;
    if (bn < 4) {
        // Q,K: bias (row-dependent) + f16 store, row stride 1024 (proven granularity)
        #pragma unroll
        for (int mf = 0; mf < 8; ++mf) {
            #pragma unroll
            for (int nf = 0; nf < 4; ++nf) {
                int col = bn * 256 + wn * 64 + nf * 16 + l15;
                #pragma unroll
                for (int j = 0; j < 4; ++j) {
                    int row = browg + mf * 16 + g * 4 + j;
                    float v = acc[mf][nf][j] + biasT[(row & 63) * 1536 + col];
                    qk[(size_t)row * 1024 + col] = (f16)v;
                }
            }
        }
    } else {
        // V: bias is row-independent. Transpose via LDS -> vT[win][head][d][s]
        // (f16x4-packed writes: base sl0*2 is 8B-aligned, swizzle touches bits 4-6
        //  only, so XOR and +j*2 commute -> identical bytes, 4x fewer LDS instrs)
        __syncthreads();
        char* T = (char*)lds;   // 256 d-rows x 512 B, XOR-swizzled
        int bn2 = bn - 4;
        #pragma unroll
        for (int mf = 0; mf < 8; ++mf) {
            int sl0 = wm * 128 + mf * 16 + g * 4;       // 0..255, 8B-aligned*2
            #pragma unroll
            for (int nf = 0; nf < 4; ++nf) {
                int dl = wn * 64 + nf * 16 + l15;       // 0..255
                float bo = biasT[1024 + bn2 * 256 + dl];
                f16x4 v4 = {(f16)(acc[mf][nf][0] + bo), (f16)(acc[mf][nf][1] + bo),
                            (f16)(acc[mf][nf][2] + bo), (f16)(acc[mf][nf][3] + bo)};
                *(f16x4*)(T + dl * 512 + ((sl0 * 2) ^ ((dl & 7) << 4))) = v4;
            }
        }
        __syncthreads();
        #pragma unroll
        for (int r = 0; r < 16; ++r) {
            int c = r * 512 + tid;              // 0..8191 chunks of 16B
            int dl = c >> 5, s0 = (c & 31) * 8;
            f16x8 v = *(const f16x8*)(T + dl * 512 + ((s0 * 2) ^ ((dl & 7) << 4)));
            int gcol = bn2 * 256 + dl;          // 0..511
            int head = gcol >> 6, dd = gcol & 63;
            int win = bm * 4 + (s0 >> 6);
            *(f16x8*)(vT + (size_t)win * 32768 + head * 4096 + dd * 64 + (s0 & 63)) = v;
        }
    }
}

// ---------------- attention: swapped QK^T in-lane softmax + setprio ----------------
__global__ __launch_bounds__(512) void attn_k(
        const f16* __restrict__ qk, const f16* __restrict__ vT,
        f16* __restrict__ attn_h) {
    __shared__ __align__(16) char S[64 * 1024];   // 8 heads x 8 KB P-slices
    int tid = threadIdx.x;
    int lane = tid & 63, h = tid >> 6;   // wave = head
    int l15 = lane & 15, g = lane >> 4;
    const f16* baseqk = qk + (size_t)blockIdx.x * 65536;
    const f16* basev  = vT + (size_t)blockIdx.x * 32768 + h * 4096;
    int qc = h * 64, kc = 512 + h * 64;

    f32x4 zero4 = {0.f, 0.f, 0.f, 0.f};
    f32x4 acc[4][4];
    #pragma unroll
    for (int a = 0; a < 4; ++a)
        #pragma unroll
        for (int b = 0; b < 4; ++b) acc[a][b] = zero4;

    {   // S^T = K @ Q^T : acc[ki][qi] = S[key=ki*16+g*4+j][query=qi*16+l15]
        f16x8 qf[4][2], kf[4][2];
        #pragma unroll
        for (int mf = 0; mf < 4; ++mf)
            #pragma unroll
            for (int ks = 0; ks < 2; ++ks)
                qf[mf][ks] = *reinterpret_cast<const f16x8*>(baseqk + (size_t)(mf * 16 + l15) * 1024 + qc + ks * 32 + g * 8);
        #pragma unroll
        for (int nf = 0; nf < 4; ++nf)
            #pragma unroll
            for (int ks = 0; ks < 2; ++ks)
                kf[nf][ks] = *reinterpret_cast<const f16x8*>(baseqk + (size_t)(nf * 16 + l15) * 1024 + kc + ks * 32 + g * 8);
        __builtin_amdgcn_s_setprio(1);
        #pragma unroll
        for (int ks = 0; ks < 2; ++ks)
            #pragma unroll
            for (int ki = 0; ki < 4; ++ki)
                #pragma unroll
                for (int qi = 0; qi < 4; ++qi)
                    acc[ki][qi] = __builtin_amdgcn_mfma_f32_16x16x32_f16(kf[ki][ks], qf[qi][ks], acc[ki][qi], 0, 0, 0);
        __builtin_amdgcn_s_setprio(0);
    }

    // V fragments: contiguous f16x8 reads (B-frag: lane holds V[s][d=l15])
    f16x8 vf[4][2];
    #pragma unroll
    for (int nf = 0; nf < 4; ++nf)
        #pragma unroll
        for (int ks = 0; ks < 2; ++ks)
            vf[nf][ks] = *reinterpret_cast<const f16x8*>(basev + (nf * 16 + l15) * 64 + ks * 32 + g * 8);

    // in-lane softmax per query (16 keys in-lane + 2+2 shfl over g);
    // P^T -> LDS [query][key], f16x4-packed (base 8B-aligned, swizzle bits 4-6 commute)
    char* Sh = S + h * 8192;
    const float SC = 0.18033688011112042f;   // 0.125 * log2(e); v_exp_f32 is 2^x
    #pragma unroll
    for (int qi = 0; qi < 4; ++qi) {
        float mx = -1e30f;
        #pragma unroll
        for (int ki = 0; ki < 4; ++ki)
            #pragma unroll
            for (int j = 0; j < 4; ++j) mx = fmaxf(mx, acc[ki][qi][j]);
        mx = fmaxf(mx, __shfl_xor(mx, 16));
        mx = fmaxf(mx, __shfl_xor(mx, 32));
        float sum = 0.f;
        #pragma unroll
        for (int ki = 0; ki < 4; ++ki)
            #pragma unroll
            for (int j = 0; j < 4; ++j) {
                float e = exp2f((acc[ki][qi][j] - mx) * SC);
                acc[ki][qi][j] = e;
                sum += e;
            }
        sum += __shfl_xor(sum, 16);
        sum += __shfl_xor(sum, 32);
        float rinv = __fdividef(1.0f, sum);
        int qrow = qi * 16 + l15;
        char* rowp = Sh + qrow * 128;
        int sw = (qrow & 7) << 4;
        #pragma unroll
        for (int ki = 0; ki < 4; ++ki) {
            f16x4 p4 = {(f16)(acc[ki][qi][0] * rinv), (f16)(acc[ki][qi][1] * rinv),
                        (f16)(acc[ki][qi][2] * rinv), (f16)(acc[ki][qi][3] * rinv)};
            *(f16x4*)(rowp + (((ki * 16 + g * 4) * 2) ^ sw)) = p4;
        }
    }

    // out_h = P @ V  (own slice; wave-local, no barrier)
    f32x4 acc2[4][4];
    #pragma unroll
    for (int a = 0; a < 4; ++a)
        #pragma unroll
        for (int b = 0; b < 4; ++b) acc2[a][b] = zero4;
    __builtin_amdgcn_s_setprio(1);
    #pragma unroll
    for (int ks = 0; ks < 2; ++ks)
        #pragma unroll
        for (int mf = 0; mf < 4; ++mf) {
            int rr = mf * 16 + l15;
            f16x8 pa = *reinterpret_cast<const f16x8*>(Sh + rr * 128 + (((ks * 32 + g * 8) * 2) ^ ((rr & 7) << 4)));
            #pragma unroll
            for (int nf = 0; nf < 4; ++nf)
                acc2[mf][nf] = __builtin_amdgcn_mfma_f32_16x16x32_f16(pa, vf[nf][ks], acc2[mf][nf], 0, 0, 0);
        }
    __builtin_amdgcn_s_setprio(0);

    f16* dst = attn_h + (size_t)blockIdx.x * 64 * 512 + h * 64;
    #pragma unroll
    for (int mf = 0; mf < 4; ++mf)
        #pragma unroll
        for (int nf = 0; nf < 4; ++nf)
            #pragma unroll
            for (int j = 0; j < 4; ++j)
                dst[(size_t)(mf * 16 + g * 4 + j) * 512 + nf * 16 + l15] = (f16)acc2[mf][nf][j];
}

// ---------------- output projection: 8-phase 256x256 GEMM + scatter ----------------
__global__ void __launch_bounds__(512, 2) proj_gemm8_k(
        const f16* __restrict__ attn_h, const f16* __restrict__ Woh,
        const float* __restrict__ b_out, float* __restrict__ out, int nblk, int m0) {
    extern __shared__ f16 lds[];
    int tid = threadIdx.x;
    int lane = tid & 63, wid = tid >> 6;
    int l15 = lane & 15, g = lane >> 4;
    int wm = wid >> 2, wn = wid & 3;
    int sid = (blockIdx.x & 7) * (nblk >> 3) + (blockIdx.x >> 3);
    int bm = sid >> 1, bn = sid & 1;
    const f16* Ap = attn_h + (size_t)bm * 256 * 512;
    const f16* Bp = Woh + (size_t)bn * 256 * 512;

    int li0 = tid, li1 = tid + 512;
    int r0 = li0 >> 3, c0 = li0 & 7, r1 = li1 >> 3, c1 = li1 & 7;
    int off0 = r0 * 512 + ((c0 ^ (r0 & 7)) * 8);
    int off1 = r1 * 512 + ((c1 ^ (r1 & 7)) * 8);

    auto stage = [&](const f16* panel, int ldsbase, int tt, int h) {
        int tb = tt & 1;
        int dst = ldsbase + (tb * 2 + h) * 8192 + wid * 512;
        const f16* src = panel + h * 65536 + tt * 64;
        gload_lds16(src + off0, (void*)&lds[dst]);
        gload_lds16(src + off1, (void*)&lds[dst + 4096]);
    };

    f32x4 acc[8][4];
    f32x4 zero4 = {0.f, 0.f, 0.f, 0.f};
    #pragma unroll
    for (int a = 0; a < 8; ++a)
        #pragma unroll
        for (int b = 0; b < 4; ++b) acc[a][b] = zero4;
    f16x8 bf[4][2];

    stage(Ap, 0, 0, 0); stage(Ap, 0, 0, 1);
    stage(Bp, 32768, 0, 0); stage(Bp, 32768, 0, 1);
    stage(Ap, 0, 1, 0); stage(Ap, 0, 1, 1);
    stage(Bp, 32768, 1, 0); stage(Bp, 32768, 1, 1);
    asm volatile("s_waitcnt vmcnt(0)" ::: "memory");
    __builtin_amdgcn_s_barrier();

    #pragma unroll
    for (int tt = 0; tt < 8; ++tt) {
        int tb = tt & 1;
        const f16* Ab = &lds[(tb * 2 + wm) * 8192];
        const f16* Bb = &lds[32768 + (tb * 2 + (wn >> 1)) * 8192];
        #pragma unroll
        for (int q = 0; q < 4; ++q) {
            f16x8 af[2][2];
            #pragma unroll
            for (int ml = 0; ml < 2; ++ml) {
                int rr = (q * 2 + ml) * 16 + l15;
                #pragma unroll
                for (int ks = 0; ks < 2; ++ks)
                    af[ml][ks] = *(const f16x8*)&Ab[rr * 64 + (((ks * 4 + g) ^ (rr & 7)) * 8)];
            }
            if (q == 0) {
                #pragma unroll
                for (int nf = 0; nf < 4; ++nf) {
                    int rb = (wn & 1) * 64 + nf * 16 + l15;
                    #pragma unroll
                    for (int ks = 0; ks < 2; ++ks)
                        bf[nf][ks] = *(const f16x8*)&Bb[rb * 64 + (((ks * 4 + g) ^ (rb & 7)) * 8)];
                }
            }
            if (q <= 1) {
                if ((tt & 1) ? (tt + 1 < 8) : (tt >= 2)) stage(Ap, 0, tt + 1, q);
            } else {
                if (tt + 2 < 8) stage(Bp, 32768, tt + 2, q - 2);
            }
            __builtin_amdgcn_s_barrier();
            __builtin_amdgcn_s_setprio(1);
            #pragma unroll
            for (int ml = 0; ml < 2; ++ml)
                #pragma unroll
                for (int nf = 0; nf < 4; ++nf)
                    #pragma unroll
                    for (int ks = 0; ks < 2; ++ks)
                        acc[q * 2 + ml][nf] = __builtin_amdgcn_mfma_f32_16x16x32_f16(
                            af[ml][ks], bf[nf][ks], acc[q * 2 + ml][nf], 0, 0, 0);
            __builtin_amdgcn_s_setprio(0);
            if (q == 3) {
                if (tt < 6)       asm volatile("s_waitcnt vmcnt(4)" ::: "memory");
                else if (tt == 6) asm volatile("s_waitcnt vmcnt(0)" ::: "memory");
            }
            __builtin_amdgcn_s_barrier();
        }
    }

    int browg = bm * 256 + wm * 128, bcolg = bn * 256 + wn * 64;
    #pragma unroll
    for (int nf = 0; nf < 4; ++nf) {
        int col = bcolg + nf * 16 + l15;
        float bo = b_out[col];
        #pragma unroll
        for (int mf = 0; mf < 8; ++mf) {
            #pragma unroll
            for (int j = 0; j < 4; ++j) {
                int srow = src_row(m0 + browg + mf * 16 + g * 4 + j);
                out[(size_t)srow * 512 + col] = acc[mf][nf][j] + bo;
            }
        }
    }
}

extern "C" void kernel_launch(void* const* d_in, const int* in_sizes, int n_in,
                              void* d_out, int out_size, void* d_ws, size_t ws_size,
                              hipStream_t stream) {
    (void)in_sizes; (void)n_in; (void)out_size;
    const float* x     = (const float*)d_in[0];
    const float* pos   = (const float*)d_in[1];
    const float* W_in  = (const float*)d_in[2];
    const float* b_in  = (const float*)d_in[3];
    const float* W_out = (const float*)d_in[4];
    const float* b_out = (const float*)d_in[5];
    float* out = (float*)d_out;

    char* ws = (char*)d_ws;
    f16*   Wi_h  = (f16*)ws;                  // 1,572,864 B
    f16*   Wo_h  = (f16*)(ws + 1572864);      //   524,288 B
    float* biasT = (float*)(ws + 2097152);    //   393,216 B
    const size_t fixed = 2490368;

    // 4096 B per row: xh/attn_h (1024, aliased) + qk (2048) + vT (1024).
    // chunks=4 keeps the ~130 MB working set L3-resident (R5/R10-proven).
    int chunks = 4;
    while (chunks < 64) {
        size_t need = fixed + ((size_t)131072 / chunks) * 4096;
        if (need <= ws_size) break;
        chunks <<= 1;
    }
    int Mc = 131072 / chunks;
    f16* xh = (f16*)(ws + fixed);             // also attn_h (xh dead after qkv_gemm)
    f16* qk = (f16*)(ws + fixed + (size_t)Mc * 1024);
    f16* vT = (f16*)(ws + fixed + (size_t)Mc * 3072);
    int nblk  = (Mc / 256) * 6;
    int nblkP = (Mc / 256) * 2;

    static_cast<void>(hipFuncSetAttribute((const void*)qkv_gemm8_k,
        hipFuncAttributeMaxDynamicSharedMemorySize, 131072));
    static_cast<void>(hipFuncSetAttribute((const void*)proj_gemm8_k,
        hipFuncAttributeMaxDynamicSharedMemorySize, 131072));

    prep_weights_k<<<1024, 256, 0, stream>>>(W_in, W_out, Wi_h, Wo_h);
    prep_bias_k<<<384, 256, 0, stream>>>(pos, W_in, b_in, biasT);
    for (int c = 0; c < chunks; ++c) {
        int m0 = c * Mc;
        prep_x_k<<<Mc / 4, 256, 0, stream>>>(x, xh, m0);
        qkv_gemm8_k<<<nblk, 512, 131072, stream>>>(xh, Wi_h, biasT, qk, vT, nblk);
        attn_k<<<Mc / 64, 512, 0, stream>>>(qk, vT, xh);
        proj_gemm8_k<<<nblkP, 512, 131072, stream>>>(xh, Wo_h, b_out, out, nblkP, m0);
    }
}